// Round 4
// baseline (441.088 us; speedup 1.0000x reference)
//
#include <hip/hip_runtime.h>

// SABlock: x(4,512,64,64) -> phi/theta/g (1x1 convs, CI=256) -> f=theta^T@phi
// -> softmax -> y=a@g^T -> w_mask 1x1 conv -> out(4,512,64,64)
// All GEMMs fp16-in / fp32-accumulate on MFMA 16x16x32_f16.
// Round 4 flash: (a) TRUE lane-contiguous frag-order staging (r3's permutation
// had an l15/lq transpose -> 8-way conflicts), (b) 2q x 2kv wave split halves
// B-frag LDS read duplication, (c) wave-private softmax vs own kv-half max,
// merged once in the epilogue -> zero in-loop stats barriers.

#define BB 4
#define CC 512
#define NN_SP 4096   // H*W
#define CI 256

typedef _Float16 f16x8 __attribute__((ext_vector_type(8)));
typedef float f32x4 __attribute__((ext_vector_type(4)));

__device__ __forceinline__ void async16(const void* gsrc, void* ldst) {
  __builtin_amdgcn_global_load_lds(
      (const __attribute__((address_space(1))) unsigned int*)gsrc,
      (__attribute__((address_space(3))) unsigned int*)ldst, 16, 0, 0);
}

// ---------------- weight convert: fp32 -> f16, stack [w_phi; w_theta] ----------------
__global__ __launch_bounds__(256) void convert_w(
    const float* __restrict__ wphi, const float* __restrict__ wtheta,
    const float* __restrict__ wg, const float* __restrict__ wmask,
    _Float16* __restrict__ wpt, _Float16* __restrict__ wgh, _Float16* __restrict__ wmh) {
  int i = blockIdx.x * 256 + threadIdx.x;
  if (i < 512 * 512) {                       // wpt rows: 0..255 phi, 256..511 theta
    int row = i >> 9, k = i & 511;
    float v = (row < 256) ? wphi[row * 512 + k] : wtheta[(row - 256) * 512 + k];
    wpt[i] = (_Float16)v;
  } else if (i < 512 * 512 + 256 * 512) {
    int j = i - 512 * 512;
    wgh[j] = (_Float16)wg[j];
  } else {
    int j = i - 512 * 512 - 256 * 512;
    wmh[j] = (_Float16)wmask[j];
  }
}

// ---------------- x (B,512,4096) fp32 -> x_T (B,4096,512) f16 ----------------
__global__ __launch_bounds__(256) void transpose_x(const float* __restrict__ x,
                                                   _Float16* __restrict__ xT) {
  __shared__ float tile[64][65];   // +1 pad: conflict-free column read
  const int n0 = blockIdx.x * 64, c0 = blockIdx.y * 64, b = blockIdx.z;
  const int tx = threadIdx.x & 63, ty = threadIdx.x >> 6;
  const float* xb = x + (long long)b * CC * NN_SP;
#pragma unroll
  for (int i = 0; i < 16; ++i) {
    int row = i * 4 + ty;
    tile[row][tx] = xb[(long long)(c0 + row) * NN_SP + n0 + tx];
  }
  __syncthreads();
  _Float16* xTb = xT + (long long)b * NN_SP * CC;
#pragma unroll
  for (int i = 0; i < 16; ++i) {
    int row = i * 4 + ty;
    xTb[(long long)(n0 + row) * CC + c0 + tx] = (_Float16)tile[tx][row];
  }
}

// ---------------- generic gemm_bt: C[m,n] = sum_k A[m,k] * Bt[n,k] ----------------
template <int M, int NT, int K, bool F16OUT>
__global__ __launch_bounds__(256, 2) void gemm_bt(
    const _Float16* __restrict__ Ab, const _Float16* __restrict__ Btb,
    void* __restrict__ Cb, long long sA, long long sB, long long sC) {
  __shared__ _Float16 As[128 * 32];
  __shared__ _Float16 Bs[128 * 32];
  const int tid = threadIdx.x, lane = tid & 63, w = tid >> 6;
  const int wm = w >> 1, wn = w & 1;
  const int l15 = lane & 15, lq = lane >> 4;
  const int b = blockIdx.z;
  const _Float16* A = Ab + (long long)b * sA;
  const _Float16* Bt = Btb + (long long)b * sB;
  const int m0 = blockIdx.y * 128, n0 = blockIdx.x * 128;

  f32x4 acc[4][4];
#pragma unroll
  for (int i = 0; i < 4; ++i)
#pragma unroll
    for (int j = 0; j < 4; ++j) acc[i][j] = (f32x4){0.f, 0.f, 0.f, 0.f};

  for (int k0 = 0; k0 < K; k0 += 32) {
    __syncthreads();
#pragma unroll
    for (int j = 0; j < 2; ++j) {
      int chw = j * 256 + w * 64;
      int ch = chw + lane;
      int row = ch >> 2, kc = ch & 3;
      async16(A + (long long)(m0 + row) * K + k0 + kc * 8, (void*)(As + chw * 8));
      async16(Bt + (long long)(n0 + row) * K + k0 + kc * 8, (void*)(Bs + chw * 8));
    }
    __syncthreads();
    f16x8 af[4], bf[4];
#pragma unroll
    for (int mt = 0; mt < 4; ++mt)
      af[mt] = *(const f16x8*)(As + (wm * 64 + mt * 16 + l15) * 32 + lq * 8);
#pragma unroll
    for (int nt = 0; nt < 4; ++nt)
      bf[nt] = *(const f16x8*)(Bs + (wn * 64 + nt * 16 + l15) * 32 + lq * 8);
#pragma unroll
    for (int mt = 0; mt < 4; ++mt)
#pragma unroll
      for (int nt = 0; nt < 4; ++nt)
        acc[mt][nt] = __builtin_amdgcn_mfma_f32_16x16x32_f16(af[mt], bf[nt], acc[mt][nt], 0, 0, 0);
  }

#pragma unroll
  for (int mt = 0; mt < 4; ++mt)
#pragma unroll
    for (int nt = 0; nt < 4; ++nt)
#pragma unroll
      for (int r = 0; r < 4; ++r) {
        int row = m0 + wm * 64 + mt * 16 + lq * 4 + r;
        int col = n0 + wn * 64 + nt * 16 + l15;
        if (F16OUT)
          ((_Float16*)Cb + (long long)b * sC)[(long long)row * NT + col] = (_Float16)acc[mt][nt][r];
        else
          ((float*)Cb + (long long)b * sC)[(long long)row * NT + col] = acc[mt][nt][r];
      }
}

// ---------------- flash attention v4 ----------------
// Block = 64 q-rows, waves (wq,wk): wq owns 32 q-rows, wk owns a 64-kv half
// of each 128-kv step. Q in regs; ring-staged phi/g in exact B-frag order
// (reads = base + lane*16B, conflict-free); wave-private online softmax
// (own-half max); single epilogue merge of (m,l,y) partials.
__global__ __launch_bounds__(256) void flash_attn4(
    const _Float16* __restrict__ pt, const _Float16* __restrict__ g,
    _Float16* __restrict__ yT) {
  __shared__ _Float16 Stg[3][8192];  // 3 x 16KB ring (48 KB)
  __shared__ _Float16 Ps[4][2048];   // per-wave P [32q][64kv] in A-frag order (16 KB)
  const int tid = threadIdx.x, lane = tid & 63, w = tid >> 6;
  const int wq = w >> 1, wk = w & 1;
  const int l15 = lane & 15, lq = lane >> 4;

  // XCD swizzle: 2 XCDs per batch
  const int idx = blockIdx.x;
  const int b = (idx >> 1) & 3;
  const int q0 = (((idx >> 3) << 1) | (idx & 1)) * 64;
  const _Float16* __restrict__ ptb = pt + (long long)b * NN_SP * 512;
  const _Float16* __restrict__ gb = g + (long long)b * CI * NN_SP;

  // Staging source offsets. Unit u = (w*4+j)*64 + lane; DMA puts lane's 16B at
  // base + (group*64+lane)*16, so the source offset uses THIS lane's (l15,lq).
  // phi chunk [128kv][64ch] -> LDS [k2(2)][nv8(8)][lane][8]:
  //   group gidx = w*4+j: k2 = gidx>>3, nv8 = gidx&7
  //   content = phi[kv0 + nv8*16 + l15][c*64 + k2*32 + lq*8 + e]
  // g chunk [64c][128kv] -> LDS [kq2(4)][ct(4)][lane][8]:
  //   kq2 = gidx>>2 = w, ct = gidx&3 = j
  //   content = g[cg*64 + ct*16 + l15][kv0 + kq2*32 + lq*8 + e]
  int offPhi[4], offG[4], chw_[4];
#pragma unroll
  for (int j = 0; j < 4; ++j) {
    int gidx = w * 4 + j;
    chw_[j] = gidx * 64;
    int k2 = gidx >> 3, nv8 = gidx & 7;
    offPhi[j] = (nv8 * 16 + l15) * 512 + k2 * 32 + lq * 8;
    offG[j] = (j * 16 + l15) * 4096 + w * 32 + lq * 8;
  }

  // Q (theta) resident: rows q0+wq*32 .. +31, 2 m-tiles x 8 k-chunks (64 VGPR)
  f16x8 qreg[2][8];
#pragma unroll
  for (int mt = 0; mt < 2; ++mt)
#pragma unroll
    for (int kk = 0; kk < 8; ++kk)
      qreg[mt][kk] = *(const f16x8*)(
          ptb + (long long)(q0 + wq * 32 + mt * 16 + l15) * 512 + 256 + kk * 32 + lq * 8);

  f32x4 yacc[2][16];
#pragma unroll
  for (int mt = 0; mt < 2; ++mt)
#pragma unroll
    for (int nt = 0; nt < 16; ++nt) yacc[mt][nt] = (f32x4){0.f, 0.f, 0.f, 0.f};
  float mrow[2][4], lrow[2][4];
#pragma unroll
  for (int mt = 0; mt < 2; ++mt)
#pragma unroll
    for (int r = 0; r < 4; ++r) { mrow[mt][r] = -3e38f; lrow[mt][r] = 0.f; }

  auto issue = [&](int q, int bi) {
    if (q >= 256) return;
    _Float16* buf = Stg[bi];
    int tq = q >> 3, sub = q & 7, kv0 = tq * 128;
    if (sub < 4) {
      const _Float16* basep = ptb + kv0 * 512 + sub * 64;
#pragma unroll
      for (int j = 0; j < 4; ++j) async16(basep + offPhi[j], (void*)(buf + chw_[j] * 8));
    } else {
      const _Float16* baseg = gb + (sub - 4) * 64 * 4096 + kv0;
#pragma unroll
      for (int j = 0; j < 4; ++j) async16(baseg + offG[j], (void*)(buf + chw_[j] * 8));
    }
  };

  int p = 0, bcur = 0;
  issue(0, 0);
  issue(1, 1);

  for (int t = 0; t < 32; ++t) {
    f32x4 S[2][4];
#pragma unroll
    for (int mt = 0; mt < 2; ++mt)
#pragma unroll
      for (int nv = 0; nv < 4; ++nv) S[mt][nv] = (f32x4){0.f, 0.f, 0.f, 0.f};

    // ---- 4 phi phases: S = theta @ phi^T over this wave's 64 kv ----
#pragma unroll
    for (int c = 0; c < 4; ++c) {
      asm volatile("s_waitcnt vmcnt(4)" ::: "memory");
      asm volatile("s_barrier" ::: "memory");
      int bn = bcur + 2; if (bn >= 3) bn -= 3;
      issue(p + 2, bn);
      const _Float16* buf = Stg[bcur];
#pragma unroll
      for (int k2 = 0; k2 < 2; ++k2)
#pragma unroll
        for (int nv = 0; nv < 4; ++nv) {
          f16x8 bf = *(const f16x8*)(buf + ((k2 * 8 + wk * 4 + nv) * 64 + lane) * 8);
          S[0][nv] = __builtin_amdgcn_mfma_f32_16x16x32_f16(qreg[0][c * 2 + k2], bf, S[0][nv], 0, 0, 0);
          S[1][nv] = __builtin_amdgcn_mfma_f32_16x16x32_f16(qreg[1][c * 2 + k2], bf, S[1][nv], 0, 0, 0);
        }
      ++p; ++bcur; if (bcur == 3) bcur = 0;
    }

    // ---- wave-private online softmax over own 64 kv (no cross-wave sync) ----
#pragma unroll
    for (int mt = 0; mt < 2; ++mt) {
      float alpha[4];
#pragma unroll
      for (int r = 0; r < 4; ++r) {
        float mx = fmaxf(fmaxf(S[mt][0][r], S[mt][1][r]), fmaxf(S[mt][2][r], S[mt][3][r]));
#pragma unroll
        for (int d = 1; d < 16; d <<= 1) mx = fmaxf(mx, __shfl_xor(mx, d, 64));
        float nm = fmaxf(mrow[mt][r], mx);
        alpha[r] = __expf(mrow[mt][r] - nm);
        mrow[mt][r] = nm;
        float ps = 0.f;
#pragma unroll
        for (int nv = 0; nv < 4; ++nv) {
          float pv = __expf(S[mt][nv][r] - nm);
          S[mt][nv][r] = pv;
          ps += pv;
        }
#pragma unroll
        for (int d = 1; d < 16; d <<= 1) ps += __shfl_xor(ps, d, 64);
        lrow[mt][r] = lrow[mt][r] * alpha[r] + ps;
      }
      f32x4 al = {alpha[0], alpha[1], alpha[2], alpha[3]};
#pragma unroll
      for (int nt = 0; nt < 16; ++nt) yacc[mt][nt] *= al;
    }

    // ---- P -> wave-private LDS in A-frag order (reads will be lane-contig) ----
#pragma unroll
    for (int mt = 0; mt < 2; ++mt)
#pragma unroll
      for (int nv = 0; nv < 4; ++nv) {
        int kq = nv >> 1;
        int lqr = (nv & 1) * 2 + (l15 >> 3);
        int e = l15 & 7;
#pragma unroll
        for (int r = 0; r < 4; ++r) {
          int u = (mt * 2 + kq) * 64 + lqr * 16 + lq * 4 + r;
          Ps[w][u * 8 + e] = (_Float16)S[mt][nv][r];
        }
      }
    f16x8 aP[2][2];
#pragma unroll
    for (int mt = 0; mt < 2; ++mt)
#pragma unroll
      for (int kq = 0; kq < 2; ++kq)
        aP[mt][kq] = *(const f16x8*)(&Ps[w][((mt * 2 + kq) * 64 + lane) * 8]);

    // ---- 4 g phases: y += P @ g^T over this wave's 64 kv ----
#pragma unroll
    for (int cg = 0; cg < 4; ++cg) {
      if (cg == 3) {
        if (t == 31) { asm volatile("s_waitcnt vmcnt(0)" ::: "memory"); }
        else         { asm volatile("s_waitcnt vmcnt(4)" ::: "memory"); }
      } else {
        asm volatile("s_waitcnt vmcnt(4)" ::: "memory");
      }
      asm volatile("s_barrier" ::: "memory");
      int bn = bcur + 2; if (bn >= 3) bn -= 3;
      issue(p + 2, bn);
      const _Float16* buf = Stg[bcur];
#pragma unroll
      for (int kq = 0; kq < 2; ++kq)
#pragma unroll
        for (int ct = 0; ct < 4; ++ct) {
          f16x8 bg = *(const f16x8*)(buf + (((wk * 2 + kq) * 4 + ct) * 64 + lane) * 8);
          yacc[0][cg * 4 + ct] =
              __builtin_amdgcn_mfma_f32_16x16x32_f16(aP[0][kq], bg, yacc[0][cg * 4 + ct], 0, 0, 0);
          yacc[1][cg * 4 + ct] =
              __builtin_amdgcn_mfma_f32_16x16x32_f16(aP[1][kq], bg, yacc[1][cg * 4 + ct], 0, 0, 0);
        }
      ++p; ++bcur; if (bcur == 3) bcur = 0;
    }
  }

  // ---- epilogue: merge wk partials (y, m, l), normalize, store yT ----
  float* EpF = (float*)&Stg[0][0];   // 32 KB per round (aliases ring, loop done)
  float* ML = (float*)&Ps[0][0];     // [wq][32 rows][2] floats
  _Float16* yTb = yT + (long long)b * NN_SP * CI;
  float s0[2][4], s1[2][4];
#pragma unroll
  for (int mt = 0; mt < 2; ++mt) {
    __syncthreads();
    if (wk == 1) {
#pragma unroll
      for (int nt = 0; nt < 16; ++nt)
        *(f32x4*)(EpF + ((wq * 16 + nt) * 64 + lane) * 4) = yacc[mt][nt];
      if (mt == 0 && l15 == 0) {
#pragma unroll
        for (int m2 = 0; m2 < 2; ++m2)
#pragma unroll
          for (int r = 0; r < 4; ++r) {
            int row = m2 * 16 + lq * 4 + r;
            ML[(wq * 32 + row) * 2 + 0] = mrow[m2][r];
            ML[(wq * 32 + row) * 2 + 1] = lrow[m2][r];
          }
      }
    }
    __syncthreads();
    if (wk == 0) {
      if (mt == 0) {
#pragma unroll
        for (int m2 = 0; m2 < 2; ++m2)
#pragma unroll
          for (int r = 0; r < 4; ++r) {
            int row = m2 * 16 + lq * 4 + r;
            float m1 = ML[(wq * 32 + row) * 2 + 0];
            float l1 = ML[(wq * 32 + row) * 2 + 1];
            float M = fmaxf(mrow[m2][r], m1);
            float f0 = __expf(mrow[m2][r] - M), f1 = __expf(m1 - M);
            float L = lrow[m2][r] * f0 + l1 * f1;
            s0[m2][r] = f0 / L;
            s1[m2][r] = f1 / L;
          }
      }
#pragma unroll
      for (int nt = 0; nt < 16; ++nt) {
        f32x4 o1 = *(const f32x4*)(EpF + ((wq * 16 + nt) * 64 + lane) * 4);
#pragma unroll
        for (int r = 0; r < 4; ++r) {
          int row = q0 + wq * 32 + mt * 16 + lq * 4 + r;
          float v = yacc[mt][nt][r] * s0[mt][r] + o1[r] * s1[mt][r];
          yTb[(long long)row * CI + nt * 16 + l15] = (_Float16)v;
        }
      }
    }
  }
}

extern "C" void kernel_launch(void* const* d_in, const int* in_sizes, int n_in,
                              void* d_out, int out_size, void* d_ws, size_t ws_size,
                              hipStream_t stream) {
  const float* x = (const float*)d_in[0];
  const float* w_phi = (const float*)d_in[1];
  const float* w_theta = (const float*)d_in[2];
  const float* w_g = (const float*)d_in[3];
  const float* w_mask = (const float*)d_in[4];
  float* out = (float*)d_out;
  char* ws = (char*)d_ws;

  _Float16* xT = (_Float16*)(ws);                 // (B,4096,512)  16.78 MB
  _Float16* pt = (_Float16*)(ws + 16777216);      // (B,4096,512)  16.78 MB  [phi|theta]
  _Float16* gB = (_Float16*)(ws + 33554432);      // (B,256,4096)   8.39 MB
  _Float16* yT = (_Float16*)(ws + 41943040);      // (B,4096,256)   8.39 MB
  _Float16* wpt = (_Float16*)(ws + 50331648);     // (512,512)
  _Float16* wg = (_Float16*)(ws + 50855936);      // (256,512)
  _Float16* wm = (_Float16*)(ws + 51118080);      // (512,256)

  convert_w<<<2048, 256, 0, stream>>>(w_phi, w_theta, w_g, w_mask, wpt, wg, wm);
  transpose_x<<<dim3(64, 8, 4), 256, 0, stream>>>(x, xT);
  gemm_bt<4096, 512, 512, true><<<dim3(4, 32, 4), 256, 0, stream>>>(
      xT, wpt, pt, 4096LL * 512, 0, 4096LL * 512);
  gemm_bt<256, 4096, 512, true><<<dim3(32, 2, 4), 256, 0, stream>>>(
      wg, xT, gB, 0, 4096LL * 512, 256LL * 4096);
  flash_attn4<<<dim3(256), 256, 0, stream>>>(pt, gB, yT);
  gemm_bt<512, 4096, 256, false><<<dim3(32, 4, 4), 256, 0, stream>>>(
      wm, yT, out, 0, 4096LL * 256, 512LL * 4096);
}

// Round 6
// 363.018 us; speedup vs baseline: 1.2151x; 1.2151x over previous
//
#include <hip/hip_runtime.h>

// SABlock: x(4,512,64,64) -> phi/theta/g (1x1 convs, CI=256) -> f=theta^T@phi
// -> softmax -> y=a@g^T -> w_mask 1x1 conv -> out(4,512,64,64)
// All GEMMs fp16-in / fp32-accumulate on MFMA 16x16x32_f16.
// Round 5 flash: 512-thr blocks (2 waves/SIMD for latency hiding), BQ=128,
// kv split across blocks (traffic 1 GB -> 0.5 GB) with (m,l,y)-partial merge
// kernel; packed-f16 max trees; l-reduction deferred to epilogue; 64 KB LDS.

#define BB 4
#define CC 512
#define NN_SP 4096   // H*W
#define CI 256

typedef _Float16 f16x8 __attribute__((ext_vector_type(8)));
typedef _Float16 f16x2 __attribute__((ext_vector_type(2)));
typedef float f32x4 __attribute__((ext_vector_type(4)));

__device__ __forceinline__ void async16(const void* gsrc, void* ldst) {
  __builtin_amdgcn_global_load_lds(
      (const __attribute__((address_space(1))) unsigned int*)gsrc,
      (__attribute__((address_space(3))) unsigned int*)ldst, 16, 0, 0);
}

// ---------------- weight convert: fp32 -> f16, stack [w_phi; w_theta] ----------------
__global__ __launch_bounds__(256) void convert_w(
    const float* __restrict__ wphi, const float* __restrict__ wtheta,
    const float* __restrict__ wg, const float* __restrict__ wmask,
    _Float16* __restrict__ wpt, _Float16* __restrict__ wgh, _Float16* __restrict__ wmh) {
  int i = blockIdx.x * 256 + threadIdx.x;
  if (i < 512 * 512) {
    int row = i >> 9, k = i & 511;
    float v = (row < 256) ? wphi[row * 512 + k] : wtheta[(row - 256) * 512 + k];
    wpt[i] = (_Float16)v;
  } else if (i < 512 * 512 + 256 * 512) {
    int j = i - 512 * 512;
    wgh[j] = (_Float16)wg[j];
  } else {
    int j = i - 512 * 512 - 256 * 512;
    wmh[j] = (_Float16)wmask[j];
  }
}

// ---------------- x (B,512,4096) fp32 -> x_T (B,4096,512) f16 ----------------
__global__ __launch_bounds__(256) void transpose_x(const float* __restrict__ x,
                                                   _Float16* __restrict__ xT) {
  __shared__ float tile[64][65];
  const int n0 = blockIdx.x * 64, c0 = blockIdx.y * 64, b = blockIdx.z;
  const int tx = threadIdx.x & 63, ty = threadIdx.x >> 6;
  const float* xb = x + (long long)b * CC * NN_SP;
#pragma unroll
  for (int i = 0; i < 16; ++i) {
    int row = i * 4 + ty;
    tile[row][tx] = xb[(long long)(c0 + row) * NN_SP + n0 + tx];
  }
  __syncthreads();
  _Float16* xTb = xT + (long long)b * NN_SP * CC;
#pragma unroll
  for (int i = 0; i < 16; ++i) {
    int row = i * 4 + ty;
    xTb[(long long)(n0 + row) * CC + c0 + tx] = (_Float16)tile[tx][row];
  }
}

// ---------------- generic gemm_bt: C[m,n] = sum_k A[m,k] * Bt[n,k] ----------------
template <int M, int NT, int K, bool F16OUT>
__global__ __launch_bounds__(256, 2) void gemm_bt(
    const _Float16* __restrict__ Ab, const _Float16* __restrict__ Btb,
    void* __restrict__ Cb, long long sA, long long sB, long long sC) {
  __shared__ _Float16 As[128 * 32];
  __shared__ _Float16 Bs[128 * 32];
  const int tid = threadIdx.x, lane = tid & 63, w = tid >> 6;
  const int wm = w >> 1, wn = w & 1;
  const int l15 = lane & 15, lq = lane >> 4;
  const int b = blockIdx.z;
  const _Float16* A = Ab + (long long)b * sA;
  const _Float16* Bt = Btb + (long long)b * sB;
  const int m0 = blockIdx.y * 128, n0 = blockIdx.x * 128;

  f32x4 acc[4][4];
#pragma unroll
  for (int i = 0; i < 4; ++i)
#pragma unroll
    for (int j = 0; j < 4; ++j) acc[i][j] = (f32x4){0.f, 0.f, 0.f, 0.f};

  for (int k0 = 0; k0 < K; k0 += 32) {
    __syncthreads();
#pragma unroll
    for (int j = 0; j < 2; ++j) {
      int chw = j * 256 + w * 64;
      int ch = chw + lane;
      int row = ch >> 2, kc = ch & 3;
      async16(A + (long long)(m0 + row) * K + k0 + kc * 8, (void*)(As + chw * 8));
      async16(Bt + (long long)(n0 + row) * K + k0 + kc * 8, (void*)(Bs + chw * 8));
    }
    __syncthreads();
    f16x8 af[4], bf[4];
#pragma unroll
    for (int mt = 0; mt < 4; ++mt)
      af[mt] = *(const f16x8*)(As + (wm * 64 + mt * 16 + l15) * 32 + lq * 8);
#pragma unroll
    for (int nt = 0; nt < 4; ++nt)
      bf[nt] = *(const f16x8*)(Bs + (wn * 64 + nt * 16 + l15) * 32 + lq * 8);
#pragma unroll
    for (int mt = 0; mt < 4; ++mt)
#pragma unroll
      for (int nt = 0; nt < 4; ++nt)
        acc[mt][nt] = __builtin_amdgcn_mfma_f32_16x16x32_f16(af[mt], bf[nt], acc[mt][nt], 0, 0, 0);
  }

#pragma unroll
  for (int mt = 0; mt < 4; ++mt)
#pragma unroll
    for (int nt = 0; nt < 4; ++nt)
#pragma unroll
      for (int r = 0; r < 4; ++r) {
        int row = m0 + wm * 64 + mt * 16 + lq * 4 + r;
        int col = n0 + wn * 64 + nt * 16 + l15;
        if (F16OUT)
          ((_Float16*)Cb + (long long)b * sC)[(long long)row * NT + col] = (_Float16)acc[mt][nt][r];
        else
          ((float*)Cb + (long long)b * sC)[(long long)row * NT + col] = acc[mt][nt][r];
      }
}

// ---------------- flash attention v5 ----------------
// 512 threads = 8 waves = 4 wq (32 q-rows each; BQ=128) x 2 wk (64-kv halves).
// Grid 256: qtile(32) x batch(4) x kvhalf(2); each block sweeps 2048 kv.
// Ring-staged phi/g in exact B-frag order; raw s_barrier + vmcnt(2);
// per-lane online l (trees deferred); packed-f16 max trees; partial
// (m,l,y) written to ws, merged by merge_y.
__global__ __launch_bounds__(512, 2) void flash5(
    const _Float16* __restrict__ pt, const _Float16* __restrict__ g,
    _Float16* __restrict__ yP, float* __restrict__ mlP) {
  __shared__ _Float16 smem[32768];   // 64 KB: [0,24576) ring 3x16KB, [24576,32768) Ps
  const int tid = threadIdx.x, lane = tid & 63, w = tid >> 6;  // w 0..7
  const int wq = w >> 1, wk = w & 1;
  const int l15 = lane & 15, lq = lane >> 4;

  const int idx = blockIdx.x;
  const int b = (idx >> 1) & 3;       // XCD pair {2b,2b+1}
  const int h = idx & 1;              // kv half; one half per XCD
  const int q0 = (idx >> 3) * 128;
  const int kvbase = h * 2048;
  const _Float16* __restrict__ ptb = pt + (long long)b * NN_SP * 512;
  const _Float16* __restrict__ gb = g + (long long)b * CI * NN_SP;

  // staging source offsets; DMA deposits lane's 16B at base + lane*16
  int offPhi[2], offG[2], chw_[2];
#pragma unroll
  for (int j = 0; j < 2; ++j) {
    int gidx = w * 2 + j;             // 0..15
    chw_[j] = gidx * 512;             // f16 offset of group base
    offPhi[j] = ((gidx & 7) * 16 + l15) * 512 + (gidx >> 3) * 32 + lq * 8;
    offG[j] = ((gidx & 3) * 16 + l15) * 4096 + (gidx >> 2) * 32 + lq * 8;
  }

  // Q (theta) resident: rows q0+wq*32..+31, 2 m-tiles x 8 k-chunks (64 VGPR)
  f16x8 qreg[2][8];
#pragma unroll
  for (int mt = 0; mt < 2; ++mt)
#pragma unroll
    for (int kk = 0; kk < 8; ++kk)
      qreg[mt][kk] = *(const f16x8*)(
          ptb + (long long)(q0 + wq * 32 + mt * 16 + l15) * 512 + 256 + kk * 32 + lq * 8);

  f32x4 yacc[2][16];
#pragma unroll
  for (int mt = 0; mt < 2; ++mt)
#pragma unroll
    for (int nt = 0; nt < 16; ++nt) yacc[mt][nt] = (f32x4){0.f, 0.f, 0.f, 0.f};
  float mrow[2][4], lsum[2][4];
#pragma unroll
  for (int mt = 0; mt < 2; ++mt)
#pragma unroll
    for (int r = 0; r < 4; ++r) { mrow[mt][r] = -3e38f; lsum[mt][r] = 0.f; }

  auto issue = [&](int q, int bi) {
    if (q >= 128) return;
    _Float16* buf = smem + bi * 8192;
    int tq = q >> 3, sub = q & 7;
    int kv0 = kvbase + tq * 128;
    if (sub < 4) {
      const _Float16* basep = ptb + (long long)kv0 * 512 + sub * 64;
      async16(basep + offPhi[0], (void*)(buf + chw_[0]));
      async16(basep + offPhi[1], (void*)(buf + chw_[1]));
    } else {
      const _Float16* baseg = gb + (long long)(sub - 4) * 64 * 4096 + kv0;
      async16(baseg + offG[0], (void*)(buf + chw_[0]));
      async16(baseg + offG[1], (void*)(buf + chw_[1]));
    }
  };

  int p = 0, bcur = 0;
  issue(0, 0);
  issue(1, 1);

  for (int t = 0; t < 16; ++t) {
    f32x4 S[2][4];
#pragma unroll
    for (int mt = 0; mt < 2; ++mt)
#pragma unroll
      for (int nv = 0; nv < 4; ++nv) S[mt][nv] = (f32x4){0.f, 0.f, 0.f, 0.f};

    // ---- 4 phi phases: S = theta @ phi^T over this wave's 64 kv ----
#pragma unroll
    for (int c = 0; c < 4; ++c) {
      asm volatile("s_waitcnt vmcnt(2)" ::: "memory");
      asm volatile("s_barrier" ::: "memory");
      int bn = bcur + 2; if (bn >= 3) bn -= 3;
      issue(p + 2, bn);
      const _Float16* buf = smem + bcur * 8192;
#pragma unroll
      for (int k2 = 0; k2 < 2; ++k2)
#pragma unroll
        for (int nv = 0; nv < 4; ++nv) {
          f16x8 bf = *(const f16x8*)(buf + ((k2 * 8 + wk * 4 + nv) * 64 + lane) * 8);
          S[0][nv] = __builtin_amdgcn_mfma_f32_16x16x32_f16(qreg[0][c * 2 + k2], bf, S[0][nv], 0, 0, 0);
          S[1][nv] = __builtin_amdgcn_mfma_f32_16x16x32_f16(qreg[1][c * 2 + k2], bf, S[1][nv], 0, 0, 0);
        }
      ++p; ++bcur; if (bcur == 3) bcur = 0;
    }

    // ---- online softmax: packed-f16 max trees, per-lane l (no sum trees) ----
#pragma unroll
    for (int r = 0; r < 4; ++r) {
      float a0 = fmaxf(fmaxf(S[0][0][r], S[0][1][r]), fmaxf(S[0][2][r], S[0][3][r]));
      float a1 = fmaxf(fmaxf(S[1][0][r], S[1][1][r]), fmaxf(S[1][2][r], S[1][3][r]));
      f16x2 hm;
      hm[0] = (_Float16)a0;
      hm[1] = (_Float16)a1;
#pragma unroll
      for (int d = 1; d < 16; d <<= 1) {
        int sv = __shfl_xor(*(int*)&hm, d, 64);
        f16x2 o = *(f16x2*)&sv;
        hm[0] = (hm[0] > o[0]) ? hm[0] : o[0];
        hm[1] = (hm[1] > o[1]) ? hm[1] : o[1];
      }
      float mx0 = (float)hm[0], mx1 = (float)hm[1];
      // mt = 0
      {
        float nm = fmaxf(mrow[0][r], mx0);
        float al = __expf(mrow[0][r] - nm);
        mrow[0][r] = nm;
        float ps = 0.f;
#pragma unroll
        for (int nv = 0; nv < 4; ++nv) {
          float pv = __expf(S[0][nv][r] - nm);
          S[0][nv][r] = pv; ps += pv;
        }
        lsum[0][r] = lsum[0][r] * al + ps;
#pragma unroll
        for (int nt = 0; nt < 16; ++nt) yacc[0][nt][r] *= al;
      }
      // mt = 1
      {
        float nm = fmaxf(mrow[1][r], mx1);
        float al = __expf(mrow[1][r] - nm);
        mrow[1][r] = nm;
        float ps = 0.f;
#pragma unroll
        for (int nv = 0; nv < 4; ++nv) {
          float pv = __expf(S[1][nv][r] - nm);
          S[1][nv][r] = pv; ps += pv;
        }
        lsum[1][r] = lsum[1][r] * al + ps;
#pragma unroll
        for (int nt = 0; nt < 16; ++nt) yacc[1][nt][r] *= al;
      }
    }

    // ---- P -> wave-private 2KB LDS in A-frag order, per mt (reused) ----
    _Float16* Pw = smem + 24576 + w * 1024;
    f16x8 aP[2][2];
#pragma unroll
    for (int mt = 0; mt < 2; ++mt) {
#pragma unroll
      for (int nv = 0; nv < 4; ++nv) {
        int kq = nv >> 1;
        int lqr = (nv & 1) * 2 + (l15 >> 3);
        int e = l15 & 7;
#pragma unroll
        for (int r = 0; r < 4; ++r) {
          int u = kq * 64 + lqr * 16 + lq * 4 + r;
          Pw[u * 8 + e] = (_Float16)S[mt][nv][r];
        }
      }
#pragma unroll
      for (int kq = 0; kq < 2; ++kq)
        aP[mt][kq] = *(const f16x8*)(Pw + (kq * 64 + lane) * 8);
    }

    // ---- 4 g phases: y += P @ g^T over this wave's 64 kv ----
#pragma unroll
    for (int cg = 0; cg < 4; ++cg) {
      if (t == 15 && cg == 3) {
        asm volatile("s_waitcnt vmcnt(0)" ::: "memory");
      } else {
        asm volatile("s_waitcnt vmcnt(2)" ::: "memory");
      }
      asm volatile("s_barrier" ::: "memory");
      int bn = bcur + 2; if (bn >= 3) bn -= 3;
      issue(p + 2, bn);
      const _Float16* buf = smem + bcur * 8192;
#pragma unroll
      for (int kq = 0; kq < 2; ++kq)
#pragma unroll
        for (int ct = 0; ct < 4; ++ct) {
          f16x8 bg = *(const f16x8*)(buf + (((wk * 2 + kq) * 4 + ct) * 64 + lane) * 8);
          yacc[0][cg * 4 + ct] =
              __builtin_amdgcn_mfma_f32_16x16x32_f16(aP[0][kq], bg, yacc[0][cg * 4 + ct], 0, 0, 0);
          yacc[1][cg * 4 + ct] =
              __builtin_amdgcn_mfma_f32_16x16x32_f16(aP[1][kq], bg, yacc[1][cg * 4 + ct], 0, 0, 0);
        }
      ++p; ++bcur; if (bcur == 3) bcur = 0;
    }
  }

  // ---- epilogue: reduce l over l15; merge wk pair; write (m,l,y) partials ----
  float lred[2][4];
#pragma unroll
  for (int mt = 0; mt < 2; ++mt)
#pragma unroll
    for (int r = 0; r < 4; ++r) {
      float s = lsum[mt][r];
#pragma unroll
      for (int d = 1; d < 16; d <<= 1) s += __shfl_xor(s, d, 64);
      lred[mt][r] = s;
    }

  float* mlbuf = (float*)smem;            // [4wq*32 rows][2]
  __syncthreads();
  if (wk == 1 && l15 == 0) {
#pragma unroll
    for (int mt = 0; mt < 2; ++mt)
#pragma unroll
      for (int r = 0; r < 4; ++r) {
        int row = wq * 32 + mt * 16 + lq * 4 + r;
        mlbuf[row * 2 + 0] = mrow[mt][r];
        mlbuf[row * 2 + 1] = lred[mt][r];
      }
  }
  __syncthreads();
  float s0[2][4], s1[2][4];
  const long long mlbase = ((long long)h * 4 + b) * 4096 + q0;
  if (wk == 0) {
#pragma unroll
    for (int mt = 0; mt < 2; ++mt)
#pragma unroll
      for (int r = 0; r < 4; ++r) {
        int row = wq * 32 + mt * 16 + lq * 4 + r;
        float m1 = mlbuf[row * 2 + 0], l1 = mlbuf[row * 2 + 1];
        float M = fmaxf(mrow[mt][r], m1);
        float e0 = __expf(mrow[mt][r] - M), e1 = __expf(m1 - M);
        s0[mt][r] = e0; s1[mt][r] = e1;
        if (l15 == 0) {
          mlP[(mlbase + row) * 2 + 0] = M;
          mlP[(mlbase + row) * 2 + 1] = lred[mt][r] * e0 + l1 * e1;
        }
      }
  }

  _Float16* yPb = yP + ((long long)h * 4 + b) * NN_SP * CI;
  float* yx = (float*)smem;               // full 64 KB exchange
#pragma unroll
  for (int mt = 0; mt < 2; ++mt) {
    __syncthreads();
    if (wk == 1) {
#pragma unroll
      for (int nt = 0; nt < 16; ++nt)
        *(f32x4*)(yx + ((wq * 16 + nt) * 64 + lane) * 4) = yacc[mt][nt];
    }
    __syncthreads();
    if (wk == 0) {
#pragma unroll
      for (int nt = 0; nt < 16; ++nt) {
        f32x4 o1 = *(const f32x4*)(yx + ((wq * 16 + nt) * 64 + lane) * 4);
#pragma unroll
        for (int r = 0; r < 4; ++r) {
          int row = q0 + wq * 32 + mt * 16 + lq * 4 + r;
          float v = yacc[mt][nt][r] * s0[mt][r] + o1[r] * s1[mt][r];
          yPb[(long long)row * CI + nt * 16 + l15] = (_Float16)v;
        }
      }
    }
  }
}

// ---------------- merge kv-half partials -> yT f16 ----------------
__global__ __launch_bounds__(256) void merge_y(
    const _Float16* __restrict__ yP, const float* __restrict__ mlP,
    _Float16* __restrict__ yT) {
  int i = blockIdx.x * 256 + threadIdx.x;   // 524288 threads
  int rowg = i >> 5;                         // b*4096+row
  int c0 = (i & 31) * 8;
  float m0 = mlP[rowg * 2], l0 = mlP[rowg * 2 + 1];
  float m1 = mlP[(16384 + rowg) * 2], l1 = mlP[(16384 + rowg) * 2 + 1];
  float M = fmaxf(m0, m1);
  float e0 = __expf(m0 - M), e1 = __expf(m1 - M);
  float inv = 1.f / (l0 * e0 + l1 * e1);
  f16x8 a = *(const f16x8*)(yP + (long long)rowg * 256 + c0);
  f16x8 c = *(const f16x8*)(yP + 4194304LL + (long long)rowg * 256 + c0);
  f16x8 o;
#pragma unroll
  for (int e = 0; e < 8; ++e)
    o[e] = (_Float16)(((float)a[e] * e0 + (float)c[e] * e1) * inv);
  *(f16x8*)(yT + (long long)rowg * 256 + c0) = o;
}

extern "C" void kernel_launch(void* const* d_in, const int* in_sizes, int n_in,
                              void* d_out, int out_size, void* d_ws, size_t ws_size,
                              hipStream_t stream) {
  const float* x = (const float*)d_in[0];
  const float* w_phi = (const float*)d_in[1];
  const float* w_theta = (const float*)d_in[2];
  const float* w_g = (const float*)d_in[3];
  const float* w_mask = (const float*)d_in[4];
  float* out = (float*)d_out;
  char* ws = (char*)d_ws;

  // workspace (43.3 MB): xT dead after g-proj -> yP reuses it; pt dead after
  // flash -> yT reuses it.
  _Float16* xT = (_Float16*)(ws);                 // (B,4096,512)  16.78 MB
  _Float16* yP = (_Float16*)(ws);                 // [2][B,4096,256] f16, aliases xT
  _Float16* pt = (_Float16*)(ws + 16777216);      // (B,4096,512)  16.78 MB [phi|theta]
  _Float16* yT = (_Float16*)(ws + 16777216);      // (B,4096,256) f16, aliases pt
  _Float16* gB = (_Float16*)(ws + 33554432);      // (B,256,4096)   8.39 MB
  float* mlP = (float*)(ws + 41943040);           // [2][B*4096][2] f32  256 KB
  _Float16* wpt = (_Float16*)(ws + 42205184);     // (512,512)
  _Float16* wg = (_Float16*)(ws + 42729472);      // (256,512)
  _Float16* wm = (_Float16*)(ws + 42991616);      // (512,256)

  convert_w<<<2048, 256, 0, stream>>>(w_phi, w_theta, w_g, w_mask, wpt, wg, wm);
  transpose_x<<<dim3(64, 8, 4), 256, 0, stream>>>(x, xT);
  gemm_bt<4096, 512, 512, true><<<dim3(4, 32, 4), 256, 0, stream>>>(
      xT, wpt, pt, 4096LL * 512, 0, 4096LL * 512);
  gemm_bt<256, 4096, 512, true><<<dim3(32, 2, 4), 256, 0, stream>>>(
      wg, xT, gB, 0, 4096LL * 512, 256LL * 4096);
  flash5<<<dim3(256), 512, 0, stream>>>(pt, gB, yP, mlP);
  merge_y<<<dim3(2048), 256, 0, stream>>>(yP, mlP, yT);
  gemm_bt<512, 4096, 256, false><<<dim3(32, 4, 4), 256, 0, stream>>>(
      wm, yT, out, 0, 4096LL * 256, 512LL * 4096);
}